// Round 11
// baseline (1122.678 us; speedup 1.0000x reference)
//
#include <hip/hip_runtime.h>
#include <hip/hip_bf16.h>

#define B_ 512
#define T_ 49
#define I_ 96
#define H_ 1024

typedef __attribute__((ext_vector_type(4))) float f32x4;
typedef __attribute__((ext_vector_type(8))) short s16x8;

__device__ __forceinline__ unsigned short f2bf(float f) {
    unsigned int u = __float_as_uint(f);
    unsigned int r = (u + 0x7FFFu + ((u >> 16) & 1u)) >> 16;
    return (unsigned short)r;
}
__device__ __forceinline__ float sigmoidf_(float x) {
    return 1.0f / (1.0f + __expf(-x));
}
__device__ __forceinline__ float tanhf_(float x) {
    return 1.0f - 2.0f / (__expf(2.0f * x) + 1.0f);
}

__device__ __forceinline__ void gload_lds16(const unsigned short* g, unsigned short* l) {
    __builtin_amdgcn_global_load_lds(
        (const __attribute__((address_space(1))) void*)g,
        (__attribute__((address_space(3))) void*)l, 16, 0, 0);
}

// 16B h-load as two 8B AGENT-scope relaxed atomic loads -> sc0 (L1 bypass,
// served by this XCD's L2 = the coherence point for XCD-local data)
__device__ __forceinline__ s16x8 loadA16(const unsigned short* p) {
    union { unsigned long long q[2]; s16x8 v; } u;
    u.q[0] = __hip_atomic_load((const unsigned long long*)p,
                               __ATOMIC_RELAXED, __HIP_MEMORY_SCOPE_AGENT);
    u.q[1] = __hip_atomic_load((const unsigned long long*)(p + 4),
                               __ATOMIC_RELAXED, __HIP_MEMORY_SCOPE_AGENT);
    return u.v;
}

// ------------- quantize fp32 -> bf16; x transposed to [t][b][i];
// ------------- zeroes flag + ticket region (every call) -------------
__global__ void quantize_kernel(const float* __restrict__ Whh,
                                const float* __restrict__ Wih,
                                const float* __restrict__ x,
                                unsigned short* __restrict__ Whh_bf,
                                unsigned short* __restrict__ Wih_bf,
                                unsigned short* __restrict__ xT_bf,
                                unsigned int* __restrict__ bar) {
    const long stride = (long)gridDim.x * blockDim.x;
    const long idx = (long)blockIdx.x * blockDim.x + threadIdx.x;

    if (blockIdx.x == 0)
        for (int i = threadIdx.x; i < (T_ * 8 + 8) * 64; i += 256) bar[i] = 0;

    const long nWhh4 = (long)3 * H_ * H_ / 4;
    const long nWih4 = (long)3 * H_ * I_ / 4;
    const long nX4   = (long)B_ * T_ * I_ / 4;

    for (long i = idx; i < nWhh4; i += stride) {
        float4 v = ((const float4*)Whh)[i];
        ushort4 o; o.x = f2bf(v.x); o.y = f2bf(v.y); o.z = f2bf(v.z); o.w = f2bf(v.w);
        ((ushort4*)Whh_bf)[i] = o;
    }
    for (long i = idx; i < nWih4; i += stride) {
        float4 v = ((const float4*)Wih)[i];
        ushort4 o; o.x = f2bf(v.x); o.y = f2bf(v.y); o.z = f2bf(v.z); o.w = f2bf(v.w);
        ((ushort4*)Wih_bf)[i] = o;
    }
    for (long i = idx; i < nX4; i += stride) {
        float4 v = ((const float4*)x)[i];
        ushort4 o; o.x = f2bf(v.x); o.y = f2bf(v.y); o.z = f2bf(v.z); o.w = f2bf(v.w);
        const long e = i * 4;                 // flat elem idx in [b][t][i]
        const int b  = (int)(e / (T_ * I_));
        const int rm = (int)(e - (long)b * (T_ * I_));
        const int tt = rm / I_;
        const int ii = rm - tt * I_;
        ((ushort4*)xT_bf)[(((long)tt * B_ + b) * I_ + ii) >> 2] = o;
    }
}

// ---------------- persistent GRU (v7): XCD-LOCAL recurrence ----------------
// 256 blocks x 512 thr (8 waves = 4 mq x 2 nq), 1 block/CU, cooperative.
// Physical XCD x (s_getreg HW_REG_XCC_ID) owns batch rows [64x, 64x+64);
// its 32 blocks (per-XCD atomic ticket -> slot) each own a 32-j-col slice.
// h[t] is produced AND consumed within one XCD -> one coherent L2:
//   h stores: plain (CDNA L1 is write-through; drained by barrier vmcnt0)
//   h loads:  agent-relaxed atomics (sc0, L1 bypass, L2-hit ~200cy)
//   sync:     per-(t,xcd) 32-slot flag array in its own 256B region;
//             arrive = 1 plain-flag agent store after __syncthreads;
//             depart = 64-lane agent-load sweep + __all. NO fences at all.
// W gates r,z: LDS-resident 1KB tiles (conflict-free, R7-proven), 128 KiB.
// W gate n + W_ih + x: normal cached loads; L2 never invalidated -> warm 49 steps.
__global__ __launch_bounds__(512)
void gru_xcd(const unsigned short* __restrict__ Whh_bf,
             const unsigned short* __restrict__ Wih_bf,
             const unsigned short* __restrict__ xT_bf,
             const float* __restrict__ b_ih,
             const float* __restrict__ b_hh,
             unsigned short* __restrict__ hbf0,
             unsigned short* __restrict__ hbf1,
             float* __restrict__ out,
             unsigned int* __restrict__ bar)
{
    __shared__ __align__(16) unsigned short Wl[128 * 512];  // 131,072 B
    __shared__ int s_xcd, s_slot;

    const int tid = threadIdx.x;
    const int w   = tid >> 6;
    const int l   = tid & 63;
    const int l15 = l & 15;
    const int l4  = l >> 4;
    const int mq  = w >> 1;      // 0..3 : 16-row m-slice of the 64 b-rows
    const int nq  = w & 1;       // 0..1 : 16-col j-half of the 32-j slice

    // ---- claim physical-XCD work slot ----
    if (tid == 0) {
        unsigned int x;
        asm volatile("s_getreg_b32 %0, hwreg(20, 0, 32)" : "=s"(x));  // HW_REG_XCC_ID
        x &= 7;
        unsigned int sl = __hip_atomic_fetch_add(bar + (T_ * 8) * 64 + x * 64, 1u,
                                                 __ATOMIC_RELAXED,
                                                 __HIP_MEMORY_SCOPE_AGENT);
        s_xcd = (int)x;
        s_slot = (int)(sl & 31);
    }
    __syncthreads();
    const int xcd  = s_xcd;
    const int slot = s_slot;

    const int b0   = xcd * 64;            // XCD's 64 batch rows
    const int j0   = slot * 32;           // block's 32 j-cols
    const int brow = b0 + mq * 16;        // wave's 16 b-rows
    const int jg   = j0 + nq * 16 + l15;  // lane's j col

    // ---- one-time: W_hh gates r,z -> LDS tiles (async DMA) ----
    // tile p: g = p>>6 (0=r, 1=z), jh = (p>>5)&1, ks = p&31
#pragma unroll
    for (int i = 0; i < 16; ++i) {
        const int p  = w * 16 + i;
        const int g  = p >> 6;
        const int jh = (p >> 5) & 1;
        const int ks = p & 31;
        const unsigned short* src = Whh_bf
            + ((long)g * H_ + j0 + jh * 16 + l15) * H_ + ks * 32 + l4 * 8;
        gload_lds16(src, &Wl[p * 512]);   // dest wave-uniform; HW adds lane*16B
    }

    // ---- loop-invariant scalars/pointers ----
    const float bR   = b_ih[jg] + b_hh[jg];
    const float bZ   = b_ih[H_ + jg] + b_hh[H_ + jg];
    const float bihN = b_ih[2 * H_ + jg];
    const float bhhN = b_hh[2 * H_ + jg];

    const unsigned short* Vr = Wih_bf + (long)(jg) * I_ + l4 * 8;
    const unsigned short* Vz = Wih_bf + (long)(H_ + jg) * I_ + l4 * 8;
    const unsigned short* Vn = Wih_bf + (long)(2 * H_ + jg) * I_ + l4 * 8;
    const unsigned short* Wnp = Whh_bf + ((long)2 * H_ + jg) * H_ + l4 * 8;

    const unsigned short* WlR = &Wl[(nq * 32) * 512 + l * 8];        // gate r, jh=nq
    const unsigned short* WlZ = &Wl[((2 + nq) * 32) * 512 + l * 8];  // gate z, jh=nq

    float hreg[4] = {0.f, 0.f, 0.f, 0.f};

    for (int t = 0; t < T_; ++t) {
        const unsigned short* hin  = (t & 1) ? hbf1 : hbf0;
        unsigned short*       hout = (t & 1) ? hbf0 : hbf1;

        f32x4 accR  = (f32x4){0.f, 0.f, 0.f, 0.f};
        f32x4 accZ  = (f32x4){0.f, 0.f, 0.f, 0.f};
        f32x4 accNi = (f32x4){0.f, 0.f, 0.f, 0.f};
        f32x4 accNh = (f32x4){0.f, 0.f, 0.f, 0.f};

        // ---- input GEMM: gi = x_t @ W_ih^T (cached, h-independent, pre-poll) ----
        {
            const unsigned short* Ax = xT_bf + ((long)t * B_ + brow + l15) * I_ + l4 * 8;
#pragma unroll
            for (int ks = 0; ks < 3; ++ks) {
                s16x8 a  = *(const s16x8*)(Ax + ks * 32);
                s16x8 br = *(const s16x8*)(Vr + ks * 32);
                s16x8 bz = *(const s16x8*)(Vz + ks * 32);
                s16x8 bn = *(const s16x8*)(Vn + ks * 32);
                accR  = __builtin_amdgcn_mfma_f32_16x16x32_bf16(a, br, accR, 0, 0, 0);
                accZ  = __builtin_amdgcn_mfma_f32_16x16x32_bf16(a, bz, accZ, 0, 0, 0);
                accNi = __builtin_amdgcn_mfma_f32_16x16x32_bf16(a, bn, accNi, 0, 0, 0);
            }
        }

        if (t > 0) {
            // ---- poll this XCD's 32 flags for step t-1 (agent sc0 loads) ----
            const unsigned int* fl = bar + ((long)(t - 1) * 8 + xcd) * 64 + (l & 31);
            for (;;) {
                unsigned int f = __hip_atomic_load(fl, __ATOMIC_RELAXED,
                                                   __HIP_MEMORY_SCOPE_AGENT);
                if (__all(f != 0)) break;
                __builtin_amdgcn_s_sleep(1);
            }
            asm volatile("" ::: "memory");

            // ---- recurrent GEMM: A = h rows via agent-sc0 ring-8; Wn cached ring-4;
            //      gates r,z from LDS. Zero intra-block barriers. ----
            const unsigned short* Ab = hin + (long)(brow + l15) * H_ + l4 * 8;

            s16x8 ar[8], wn[4];
#pragma unroll
            for (int p = 0; p < 8; ++p) ar[p] = loadA16(Ab + p * 32);
#pragma unroll
            for (int p = 0; p < 4; ++p) wn[p] = *(const s16x8*)(Wnp + p * 32);

#pragma unroll
            for (int ks = 0; ks < 32; ++ks) {
                s16x8 a  = ar[ks & 7];
                s16x8 bn = wn[ks & 3];
                if (ks < 24) ar[ks & 7] = loadA16(Ab + (ks + 8) * 32);
                if (ks < 28) wn[ks & 3] = *(const s16x8*)(Wnp + (ks + 4) * 32);
                s16x8 br = *(const s16x8*)(WlR + ks * 512);
                s16x8 bz = *(const s16x8*)(WlZ + ks * 512);
                accR  = __builtin_amdgcn_mfma_f32_16x16x32_bf16(a, br, accR, 0, 0, 0);
                accZ  = __builtin_amdgcn_mfma_f32_16x16x32_bf16(a, bz, accZ, 0, 0, 0);
                accNh = __builtin_amdgcn_mfma_f32_16x16x32_bf16(a, bn, accNh, 0, 0, 0);
            }
        }

        // ---- epilogue: gates + blend; h state in registers ----
#pragma unroll
        for (int r = 0; r < 4; ++r) {
            const float rg = sigmoidf_(accR[r] + bR);
            const float zg = sigmoidf_(accZ[r] + bZ);
            const float ng = tanhf_(accNi[r] + bihN + rg * (accNh[r] + bhhN));
            hreg[r] = (1.0f - zg) * ng + zg * hreg[r];
            const long off = (long)(brow + l4 * 4 + r) * H_ + jg;
            if (t < T_ - 1) hout[off] = f2bf(hreg[r]);   // plain store, L1 write-through
            else            out[off]  = hreg[r];
        }

        // ---- arrive: one flag store per block into XCD-private 256B region ----
        if (t < T_ - 1) {
            __syncthreads();   // vmcnt(0): h stores are in this XCD's L2
            if (tid == 0)
                __hip_atomic_store(bar + ((long)t * 8 + xcd) * 64 + slot, 1u,
                                   __ATOMIC_RELAXED, __HIP_MEMORY_SCOPE_AGENT);
        }
    }
}

extern "C" void kernel_launch(void* const* d_in, const int* in_sizes, int n_in,
                              void* d_out, int out_size, void* d_ws, size_t ws_size,
                              hipStream_t stream) {
    const float* enc_in = (const float*)d_in[0];
    const float* W_ih   = (const float*)d_in[1];
    const float* W_hh   = (const float*)d_in[2];
    const float* b_ih   = (const float*)d_in[3];
    const float* b_hh   = (const float*)d_in[4];
    float* out = (float*)d_out;

    char* ws = (char*)d_ws;
    unsigned short* Whh_bf = (unsigned short*)(ws);             // 6,291,456 B
    unsigned short* Wih_bf = (unsigned short*)(ws + 6291456);   //   589,824 B
    unsigned short* xT_bf  = (unsigned short*)(ws + 6881280);   // 4,816,896 B
    unsigned short* hbf0   = (unsigned short*)(ws + 11698176);  // 1,048,576 B
    unsigned short* hbf1   = (unsigned short*)(ws + 12746752);  // 1,048,576 B
    unsigned int*   bar    = (unsigned int*)(ws + 13795328);    //   102,400 B

    quantize_kernel<<<dim3(1024), dim3(256), 0, stream>>>(W_hh, W_ih, enc_in,
                                                          Whh_bf, Wih_bf, xT_bf, bar);

    void* args[] = {(void*)&Whh_bf, (void*)&Wih_bf, (void*)&xT_bf,
                    (void*)&b_ih, (void*)&b_hh,
                    (void*)&hbf0, (void*)&hbf1, (void*)&out, (void*)&bar};
    hipLaunchCooperativeKernel((const void*)gru_xcd,
                               dim3(256), dim3(512), args, 0, stream);
}

// Round 12
// 792.053 us; speedup vs baseline: 1.4174x; 1.4174x over previous
//
#include <hip/hip_runtime.h>
#include <hip/hip_bf16.h>

#define B_ 512
#define T_ 49
#define I_ 96
#define H_ 1024

typedef __attribute__((ext_vector_type(4))) float f32x4;
typedef __attribute__((ext_vector_type(8))) short s16x8;

__device__ __forceinline__ unsigned short f2bf(float f) {
    unsigned int u = __float_as_uint(f);
    unsigned int r = (u + 0x7FFFu + ((u >> 16) & 1u)) >> 16;
    return (unsigned short)r;
}
__device__ __forceinline__ float sigmoidf_(float x) {
    return 1.0f / (1.0f + __expf(-x));
}
__device__ __forceinline__ float tanhf_(float x) {
    return 1.0f - 2.0f / (__expf(2.0f * x) + 1.0f);
}

__device__ __forceinline__ void gload_lds16(const unsigned short* g, unsigned short* l) {
    __builtin_amdgcn_global_load_lds(
        (const __attribute__((address_space(1))) void*)g,
        (__attribute__((address_space(3))) void*)l, 16, 0, 0);
}

// ------------- quantize fp32 -> bf16; x transposed to [t][b][i];
// ------------- zeroes flag + ticket region (every call) -------------
__global__ void quantize_kernel(const float* __restrict__ Whh,
                                const float* __restrict__ Wih,
                                const float* __restrict__ x,
                                unsigned short* __restrict__ Whh_bf,
                                unsigned short* __restrict__ Wih_bf,
                                unsigned short* __restrict__ xT_bf,
                                unsigned int* __restrict__ bar) {
    const long stride = (long)gridDim.x * blockDim.x;
    const long idx = (long)blockIdx.x * blockDim.x + threadIdx.x;

    if (blockIdx.x == 0)
        for (int i = threadIdx.x; i < (T_ * 8 + 8) * 64; i += 256) bar[i] = 0;

    const long nWhh4 = (long)3 * H_ * H_ / 4;
    const long nWih4 = (long)3 * H_ * I_ / 4;
    const long nX4   = (long)B_ * T_ * I_ / 4;

    for (long i = idx; i < nWhh4; i += stride) {
        float4 v = ((const float4*)Whh)[i];
        ushort4 o; o.x = f2bf(v.x); o.y = f2bf(v.y); o.z = f2bf(v.z); o.w = f2bf(v.w);
        ((ushort4*)Whh_bf)[i] = o;
    }
    for (long i = idx; i < nWih4; i += stride) {
        float4 v = ((const float4*)Wih)[i];
        ushort4 o; o.x = f2bf(v.x); o.y = f2bf(v.y); o.z = f2bf(v.z); o.w = f2bf(v.w);
        ((ushort4*)Wih_bf)[i] = o;
    }
    for (long i = idx; i < nX4; i += stride) {
        float4 v = ((const float4*)x)[i];
        ushort4 o; o.x = f2bf(v.x); o.y = f2bf(v.y); o.z = f2bf(v.z); o.w = f2bf(v.w);
        const long e = i * 4;                 // flat elem idx in [b][t][i]
        const int b  = (int)(e / (T_ * I_));
        const int rm = (int)(e - (long)b * (T_ * I_));
        const int tt = rm / I_;
        const int ii = rm - tt * I_;
        ((ushort4*)xT_bf)[(((long)tt * B_ + b) * I_ + ii) >> 2] = o;
    }
}

// ---------------- persistent GRU (v8): XCD-local + coalesced sc0 h-reads ----------------
// Identical structure to R11's gru_xcd (XCD claims batch slice via HW_REG_XCC_ID;
// h produced & consumed inside one coherent per-XCD L2; flag-array sync, no fences)
// with ONE change: h loads are plain coalesced global_load_dwordx4 with sc0
// (L1 bypass, normal VMEM path) instead of per-lane 8B ATOMIC loads. Atomic
// loads don't coalesce -> ~131K serialized L2 atomic ops/step/XCD was the
// hidden 13-15 us/step cost across R8-R11.
// Use-side hazard (rule #18): explicit s_waitcnt vmcnt(0) + sched_barrier(0)
// between the asm loads and any consumer.
__global__ __launch_bounds__(512)
void gru_xcd2(const unsigned short* __restrict__ Whh_bf,
              const unsigned short* __restrict__ Wih_bf,
              const unsigned short* __restrict__ xT_bf,
              const float* __restrict__ b_ih,
              const float* __restrict__ b_hh,
              unsigned short* __restrict__ hbf0,
              unsigned short* __restrict__ hbf1,
              float* __restrict__ out,
              unsigned int* __restrict__ bar)
{
    __shared__ __align__(16) unsigned short Wl[128 * 512];  // 131,072 B
    __shared__ int s_xcd, s_slot;

    const int tid = threadIdx.x;
    const int w   = tid >> 6;
    const int l   = tid & 63;
    const int l15 = l & 15;
    const int l4  = l >> 4;
    const int mq  = w >> 1;      // 0..3 : 16-row m-slice of the 64 b-rows
    const int nq  = w & 1;       // 0..1 : 16-col j-half of the 32-j slice

    // ---- claim physical-XCD work slot ----
    if (tid == 0) {
        unsigned int x;
        asm volatile("s_getreg_b32 %0, hwreg(20, 0, 32)" : "=s"(x));  // HW_REG_XCC_ID
        x &= 7;
        unsigned int sl = __hip_atomic_fetch_add(bar + (T_ * 8) * 64 + x * 64, 1u,
                                                 __ATOMIC_RELAXED,
                                                 __HIP_MEMORY_SCOPE_AGENT);
        s_xcd = (int)x;
        s_slot = (int)(sl & 31);
    }
    __syncthreads();
    const int xcd  = s_xcd;
    const int slot = s_slot;

    const int b0   = xcd * 64;            // XCD's 64 batch rows
    const int j0   = slot * 32;           // block's 32 j-cols
    const int brow = b0 + mq * 16;        // wave's 16 b-rows
    const int jg   = j0 + nq * 16 + l15;  // lane's j col

    // ---- one-time: W_hh gates r,z -> LDS tiles (async DMA) ----
    // tile p: g = p>>6 (0=r, 1=z), jh = (p>>5)&1, ks = p&31
#pragma unroll
    for (int i = 0; i < 16; ++i) {
        const int p  = w * 16 + i;
        const int g  = p >> 6;
        const int jh = (p >> 5) & 1;
        const int ks = p & 31;
        const unsigned short* src = Whh_bf
            + ((long)g * H_ + j0 + jh * 16 + l15) * H_ + ks * 32 + l4 * 8;
        gload_lds16(src, &Wl[p * 512]);   // dest wave-uniform; HW adds lane*16B
    }

    // ---- loop-invariant scalars/pointers ----
    const float bR   = b_ih[jg] + b_hh[jg];
    const float bZ   = b_ih[H_ + jg] + b_hh[H_ + jg];
    const float bihN = b_ih[2 * H_ + jg];
    const float bhhN = b_hh[2 * H_ + jg];

    const unsigned short* Vr = Wih_bf + (long)(jg) * I_ + l4 * 8;
    const unsigned short* Vz = Wih_bf + (long)(H_ + jg) * I_ + l4 * 8;
    const unsigned short* Vn = Wih_bf + (long)(2 * H_ + jg) * I_ + l4 * 8;
    const unsigned short* Wnp = Whh_bf + ((long)2 * H_ + jg) * H_ + l4 * 8;

    const unsigned short* WlR = &Wl[(nq * 32) * 512 + l * 8];        // gate r, jh=nq
    const unsigned short* WlZ = &Wl[((2 + nq) * 32) * 512 + l * 8];  // gate z, jh=nq

    float hreg[4] = {0.f, 0.f, 0.f, 0.f};

    for (int t = 0; t < T_; ++t) {
        const unsigned short* hin  = (t & 1) ? hbf1 : hbf0;
        unsigned short*       hout = (t & 1) ? hbf0 : hbf1;

        f32x4 accR  = (f32x4){0.f, 0.f, 0.f, 0.f};
        f32x4 accZ  = (f32x4){0.f, 0.f, 0.f, 0.f};
        f32x4 accNi = (f32x4){0.f, 0.f, 0.f, 0.f};
        f32x4 accNh = (f32x4){0.f, 0.f, 0.f, 0.f};

        // ---- input GEMM: gi = x_t @ W_ih^T (cached, h-independent, pre-poll) ----
        {
            const unsigned short* Ax = xT_bf + ((long)t * B_ + brow + l15) * I_ + l4 * 8;
#pragma unroll
            for (int ks = 0; ks < 3; ++ks) {
                s16x8 a  = *(const s16x8*)(Ax + ks * 32);
                s16x8 br = *(const s16x8*)(Vr + ks * 32);
                s16x8 bz = *(const s16x8*)(Vz + ks * 32);
                s16x8 bn = *(const s16x8*)(Vn + ks * 32);
                accR  = __builtin_amdgcn_mfma_f32_16x16x32_bf16(a, br, accR, 0, 0, 0);
                accZ  = __builtin_amdgcn_mfma_f32_16x16x32_bf16(a, bz, accZ, 0, 0, 0);
                accNi = __builtin_amdgcn_mfma_f32_16x16x32_bf16(a, bn, accNi, 0, 0, 0);
            }
        }

        if (t > 0) {
            // ---- wave 0 polls this XCD's 32 flags for step t-1 ----
            if (w == 0) {
                const unsigned int* fl = bar + ((long)(t - 1) * 8 + xcd) * 64 + (l & 31);
                for (;;) {
                    unsigned int f = __hip_atomic_load(fl, __ATOMIC_RELAXED,
                                                       __HIP_MEMORY_SCOPE_AGENT);
                    if (__all(f != 0)) break;
                    __builtin_amdgcn_s_sleep(1);
                }
            }
            __syncthreads();   // h[t-1] visible in this XCD's L2 for all waves

            // ---- A-rows: 32 coalesced 16B loads, sc0 (L1 bypass, L2-served) ----
            const unsigned short* Ab = hin + (long)(brow + l15) * H_ + l4 * 8;
            s16x8 a[32];
#pragma unroll
            for (int p = 0; p < 32; ++p) {
                asm volatile("global_load_dwordx4 %0, %1, off sc0"
                             : "=v"(a[p]) : "v"(Ab + p * 32));
            }

            // ---- Wn ring-4 (plain cached; L2 never invalidated -> warm) ----
            s16x8 wn[4];
#pragma unroll
            for (int p = 0; p < 4; ++p) wn[p] = *(const s16x8*)(Wnp + p * 32);

            asm volatile("s_waitcnt vmcnt(0)");
            __builtin_amdgcn_sched_barrier(0);

            // ---- recurrent GEMM: 32 k-steps; r,z from LDS, n streamed ----
#pragma unroll
            for (int ks = 0; ks < 32; ++ks) {
                s16x8 bn = wn[ks & 3];
                if (ks < 28) wn[ks & 3] = *(const s16x8*)(Wnp + (ks + 4) * 32);
                s16x8 br = *(const s16x8*)(WlR + ks * 512);
                s16x8 bz = *(const s16x8*)(WlZ + ks * 512);
                accR  = __builtin_amdgcn_mfma_f32_16x16x32_bf16(a[ks], br, accR, 0, 0, 0);
                accZ  = __builtin_amdgcn_mfma_f32_16x16x32_bf16(a[ks], bz, accZ, 0, 0, 0);
                accNh = __builtin_amdgcn_mfma_f32_16x16x32_bf16(a[ks], bn, accNh, 0, 0, 0);
            }
        }

        // ---- epilogue: gates + blend; h state in registers ----
#pragma unroll
        for (int r = 0; r < 4; ++r) {
            const float rg = sigmoidf_(accR[r] + bR);
            const float zg = sigmoidf_(accZ[r] + bZ);
            const float ng = tanhf_(accNi[r] + bihN + rg * (accNh[r] + bhhN));
            hreg[r] = (1.0f - zg) * ng + zg * hreg[r];
            const long off = (long)(brow + l4 * 4 + r) * H_ + jg;
            if (t < T_ - 1) hout[off] = f2bf(hreg[r]);   // plain store (L1 is write-through)
            else            out[off]  = hreg[r];
        }

        // ---- arrive: one flag store per block into XCD-private region ----
        if (t < T_ - 1) {
            __syncthreads();   // vmcnt(0): this block's h stores acked at L2
            if (tid == 0)
                __hip_atomic_store(bar + ((long)t * 8 + xcd) * 64 + slot, 1u,
                                   __ATOMIC_RELAXED, __HIP_MEMORY_SCOPE_AGENT);
        }
    }
}

extern "C" void kernel_launch(void* const* d_in, const int* in_sizes, int n_in,
                              void* d_out, int out_size, void* d_ws, size_t ws_size,
                              hipStream_t stream) {
    const float* enc_in = (const float*)d_in[0];
    const float* W_ih   = (const float*)d_in[1];
    const float* W_hh   = (const float*)d_in[2];
    const float* b_ih   = (const float*)d_in[3];
    const float* b_hh   = (const float*)d_in[4];
    float* out = (float*)d_out;

    char* ws = (char*)d_ws;
    unsigned short* Whh_bf = (unsigned short*)(ws);             // 6,291,456 B
    unsigned short* Wih_bf = (unsigned short*)(ws + 6291456);   //   589,824 B
    unsigned short* xT_bf  = (unsigned short*)(ws + 6881280);   // 4,816,896 B
    unsigned short* hbf0   = (unsigned short*)(ws + 11698176);  // 1,048,576 B
    unsigned short* hbf1   = (unsigned short*)(ws + 12746752);  // 1,048,576 B
    unsigned int*   bar    = (unsigned int*)(ws + 13795328);    //   102,400 B

    quantize_kernel<<<dim3(1024), dim3(256), 0, stream>>>(W_hh, W_ih, enc_in,
                                                          Whh_bf, Wih_bf, xT_bf, bar);

    void* args[] = {(void*)&Whh_bf, (void*)&Wih_bf, (void*)&xT_bf,
                    (void*)&b_ih, (void*)&b_hh,
                    (void*)&hbf0, (void*)&hbf1, (void*)&out, (void*)&bar};
    hipLaunchCooperativeKernel((const void*)gru_xcd2,
                               dim3(256), dim3(512), args, 0, stream);
}